// Round 7
// baseline (2746.996 us; speedup 1.0000x reference)
//
#include <hip/hip_runtime.h>
#include <hip/hip_bf16.h>
#include <stdint.h>

#define EMB 300
#define D1 320      // padded EMB  (mult of 32)
#define D2 640      // padded 2*EMB (mult of 32)
#define NLAYER 5

typedef __attribute__((ext_vector_type(8))) short short8v;
typedef __attribute__((ext_vector_type(4))) float f32x4;

__device__ __forceinline__ float bf2f(ushort u){
  union { uint32_t i; float f; } c; c.i = ((uint32_t)u) << 16; return c.f;
}
__device__ __forceinline__ ushort f2bf(float f){
  union { float f; uint32_t i; } c; c.f = f;
  uint32_t i = c.i;
  return (ushort)((i + 0x7FFFu + ((i >> 16) & 1u)) >> 16);
}

// ---------------- weight prep: transpose + pad + bf16 split (hi + lo residual) ----------------
__global__ void k_prep_w1(const float* __restrict__ W1, ushort* __restrict__ W1H,
                          ushort* __restrict__ W1L){
  int id = blockIdx.x * 256 + threadIdx.x;
  if (id >= NLAYER * D2 * D1) return;
  int l = id / (D2 * D1), r = id % (D2 * D1);
  int n = r / D1, k = r % D1;   // W1T[l][n][k] = W1[l][k][n]
  float v = (n < 2*EMB && k < EMB) ? W1[((size_t)l * EMB + k) * (2*EMB) + n] : 0.f;
  ushort hi = f2bf(v);
  W1H[id] = hi;
  W1L[id] = f2bf(v - bf2f(hi));
}
__global__ void k_prep_w2(const float* __restrict__ W2, ushort* __restrict__ W2H,
                          ushort* __restrict__ W2L){
  int id = blockIdx.x * 256 + threadIdx.x;
  if (id >= NLAYER * D1 * D2) return;
  int l = id / (D1 * D2), r = id % (D1 * D2);
  int n = r / D2, k = r % D2;   // W2T[l][n][k] = W2[l][k][n]
  float v = (n < EMB && k < 2*EMB) ? W2[((size_t)l * (2*EMB) + k) * EMB + n] : 0.f;
  ushort hi = f2bf(v);
  W2H[id] = hi;
  W2L[id] = f2bf(v - bf2f(hi));
}
__global__ void k_prep_vec(const float* b1, const float* b2, const float* gamma, const float* beta,
                           float* b1p, float* b2p, float* gp, float* bp, float* scsh0){
  int id = blockIdx.x * 256 + threadIdx.x;
  if (id < NLAYER * D2){
    int l = id / D2, n = id % D2;
    b1p[id] = (n < 2*EMB) ? b1[l * (2*EMB) + n] : 0.f;
  }
  if (id < NLAYER * D1){
    int l = id / D1, c = id % D1;
    b2p[id] = (c < EMB) ? b2[l * EMB + c]    : 0.f;
    gp[id]  = (c < EMB) ? gamma[l * EMB + c] : 0.f;
    bp[id]  = (c < EMB) ? beta[l * EMB + c]  : 0.f;
  }
  if (id < D1){                 // identity affine for layer 0's fused "BN"
    scsh0[id] = 1.0f;
    scsh0[D1 + id] = 0.0f;
  }
}
// initial z0 (f32 padded) + bf16 copy for the gather
__global__ void k_hinit(const float* __restrict__ nf, float* __restrict__ z,
                        ushort* __restrict__ zbf, int N){
  int id = blockIdx.x * 256 + threadIdx.x;
  if (id >= N * 80) return;
  int n = id / 80, q = id % 80;
  float4 v = make_float4(0.f, 0.f, 0.f, 0.f);
  if (q < 75) v = *(const float4*)(nf + (size_t)n * EMB + q * 4);  // 300 = 75*4
  *(float4*)(z + (size_t)n * D1 + q * 4) = v;
  ushort o[4] = {f2bf(v.x), f2bf(v.y), f2bf(v.z), f2bf(v.w)};
  *(uint2*)(zbf + (size_t)n * D1 + q * 4) = *(const uint2*)o;
}

// ---------------- CSR build (counting sort by dst) ----------------
__global__ void k_count(const int* __restrict__ dst, int* __restrict__ deg, int E){
  int e = blockIdx.x * 256 + threadIdx.x;
  if (e < E) atomicAdd(&deg[dst[e]], 1);
}
__global__ __launch_bounds__(1024) void k_scan(const int* __restrict__ deg,
                                               int* __restrict__ row_ptr,
                                               int* __restrict__ cursor, int N){
  __shared__ int wsum[16];
  __shared__ int carryS;
  int tid = threadIdx.x, lane = tid & 63, wid = tid >> 6;
  if (tid == 0) carryS = 0;
  __syncthreads();
  for (int base = 0; base < N; base += 1024){
    int i = base + tid;
    int v = (i < N) ? deg[i] : 0;
    int isc = v;
    #pragma unroll
    for (int off = 1; off < 64; off <<= 1){
      int t = __shfl_up(isc, off, 64);
      if (lane >= off) isc += t;
    }
    if (lane == 63) wsum[wid] = isc;
    __syncthreads();
    int woff = 0;
    for (int ww = 0; ww < wid; ww++) woff += wsum[ww];
    int carry = carryS;
    int excl = carry + woff + isc - v;
    if (i < N){ row_ptr[i] = excl; cursor[i] = excl; }
    __syncthreads();
    if (tid == 0){
      int s = 0;
      for (int ww = 0; ww < 16; ww++) s += wsum[ww];
      carryS = carry + s;
    }
    __syncthreads();
  }
  if (tid == 0) row_ptr[N] = carryS;
}
__global__ void k_scatter(const int* __restrict__ src, const int* __restrict__ dst,
                          int* __restrict__ cursor, int* __restrict__ ssrc, int E){
  int e = blockIdx.x * 256 + threadIdx.x;
  if (e < E){
    int p = atomicAdd(&cursor[dst[e]], 1);
    ssrc[p] = src[e];
  }
}

// ---------------- fused BN-apply + aggregation ----------------
// self term: exact f32 z; neighbor term: bf16 copy zbf (half the gather bytes).
// h = relu?(val*sc + sh); x = (1+eps)h_self + sum_neigh h[src].
// block = 320 threads = 8 nodes x 40 chunks (8 cols each)
__global__ __launch_bounds__(320) void k_aggregate(const float* __restrict__ z,
                                                   const ushort* __restrict__ zbf,
                                                   const float* __restrict__ scsh,
                                                   ushort* __restrict__ xh,
                                                   ushort* __restrict__ xl,
                                                   const int* __restrict__ row_ptr,
                                                   const int* __restrict__ ssrc,
                                                   const float* __restrict__ eps,
                                                   int l, int relu, int N){
  int t = threadIdx.x;
  int nl = t / 40, q = t % 40;
  int n = blockIdx.x * 8 + nl;
  if (n >= N) return;
  const int c0 = q * 8;
  float sc[8], sh[8];
  {
    float4 a = *(const float4*)(scsh + c0);
    float4 b = *(const float4*)(scsh + c0 + 4);
    float4 c = *(const float4*)(scsh + D1 + c0);
    float4 d = *(const float4*)(scsh + D1 + c0 + 4);
    sc[0]=a.x; sc[1]=a.y; sc[2]=a.z; sc[3]=a.w; sc[4]=b.x; sc[5]=b.y; sc[6]=b.z; sc[7]=b.w;
    sh[0]=c.x; sh[1]=c.y; sh[2]=c.z; sh[3]=c.w; sh[4]=d.x; sh[5]=d.y; sh[6]=d.z; sh[7]=d.w;
  }
  float acc[8];
  {
    const float* zp = z + (size_t)n * D1 + c0;
    float4 a = *(const float4*)zp, b = *(const float4*)(zp + 4);
    float v[8] = {a.x,a.y,a.z,a.w,b.x,b.y,b.z,b.w};
    float se = 1.0f + eps[l];
    #pragma unroll
    for (int j = 0; j < 8; j++){
      float u = fmaf(v[j], sc[j], sh[j]);
      if (relu) u = fmaxf(u, 0.f);
      acc[j] = se * u;
    }
  }
  auto accrow = [&](uint4 u){
    const ushort* us = (const ushort*)&u;
    #pragma unroll
    for (int j = 0; j < 8; j++){
      float x = fmaf(bf2f(us[j]), sc[j], sh[j]);
      if (relu) x = fmaxf(x, 0.f);
      acc[j] += x;
    }
  };
  int e0 = row_ptr[n], e1 = row_ptr[n + 1];
  int e = e0;
  for (; e + 4 <= e1; e += 4){
    int s0 = ssrc[e], s1 = ssrc[e+1], s2 = ssrc[e+2], s3 = ssrc[e+3];
    uint4 u0 = *(const uint4*)(zbf + (size_t)s0 * D1 + c0);
    uint4 u1 = *(const uint4*)(zbf + (size_t)s1 * D1 + c0);
    uint4 u2 = *(const uint4*)(zbf + (size_t)s2 * D1 + c0);
    uint4 u3 = *(const uint4*)(zbf + (size_t)s3 * D1 + c0);
    accrow(u0); accrow(u1); accrow(u2); accrow(u3);
  }
  for (; e < e1; e++){
    uint4 u = *(const uint4*)(zbf + (size_t)ssrc[e] * D1 + c0);
    accrow(u);
  }
  ushort oh[8], ol[8];
  #pragma unroll
  for (int j = 0; j < 8; j++){
    oh[j] = f2bf(acc[j]);
    ol[j] = f2bf(acc[j] - bf2f(oh[j]));
  }
  *(uint4*)(xh + (size_t)n * D1 + q * 8) = *(const uint4*)oh;
  *(uint4*)(xl + (size_t)n * D1 + q * 8) = *(const uint4*)ol;
}

// ---------------- GEMM: C = (AH+AL)[MPAD x K] * (BH+BL)[K x LDC] (+bias, relu) ----------------
// B is transposed [LDC][K]. acc += Ah*Bh + Al*Bh + Ah*Bl (Al*Bl dropped, ~2^-16 rel).
// Tile 256x64, BK=32, 4 waves on M. 1-D grid, bijective XCD-chunked (m,n) decode (T1+m204).
// LDS tiles are K-MAJOR: [granule(8 bf16 = 16B)][row] so fragment ds_read_b128 is
// bank-conflict-free (16 consecutive lanes read 256 contiguous bytes). global_load_lds
// keeps a linear LDS dest; the per-lane GLOBAL source address does the transpose.
// STATS: per-column sum/sumsq into bnacc + f32 z AND bf16 z copy (outz) for the next gather.
template<int K, int LDC, int NBN, bool RELU, bool OUTSPLIT, bool STATS>
__global__ __launch_bounds__(256) void k_gemm(const ushort* __restrict__ AH,
                                              const ushort* __restrict__ AL,
                                              const ushort* __restrict__ BH,
                                              const ushort* __restrict__ BL,
                                              const float* __restrict__ bias,
                                              ushort* __restrict__ outh,
                                              ushort* __restrict__ outl,
                                              float* __restrict__ outf,
                                              ushort* __restrict__ outz,
                                              float* __restrict__ bnacc,
                                              int Nrows){
  __shared__ ushort smem[2 * 256 * 32 + 2 * 64 * 32];
  const int tid = threadIdx.x;
  const int lane = tid & 63;
  const int w = tid >> 6;

  const int nwg = gridDim.x;
  const int q8 = nwg >> 3, r8 = nwg & 7;
  const int xcd = blockIdx.x & 7, pos = blockIdx.x >> 3;
  const int wg = (xcd < r8 ? xcd * (q8 + 1) : r8 * (q8 + 1) + (xcd - r8) * q8) + pos;
  const size_t bm = (size_t)(wg / NBN) * 256;
  const int bn = (wg % NBN) * 64;

  f32x4 acc[4][4];
  #pragma unroll
  for (int m = 0; m < 4; m++)
    #pragma unroll
    for (int n = 0; n < 4; n++)
      acc[m][n] = f32x4{0.f, 0.f, 0.f, 0.f};

  // K-major LDS: A granule block = 256 rows * 8 ushort = 2048; B block = 64 * 8 = 512.
  ushort* lAh = smem;                       // [4][256][8]
  ushort* lAl = smem + 256 * 32;            // [4][256][8]
  ushort* lBh = smem + 2 * 256 * 32;        // [4][64][8]
  ushort* lBl = smem + 2 * 256 * 32 + 64 * 32;

  for (int k0 = 0; k0 < K; k0 += 32){
    // stage A: issue i stages k-granule i, rows w*64+lane (per-lane global row stride)
    #pragma unroll
    for (int i = 0; i < 4; i++){
      int r = w * 64 + lane;
      const ushort* gh = AH + (bm + r) * K + k0 + i * 8;
      const ushort* gl = AL + (bm + r) * K + k0 + i * 8;
      ushort* lph = lAh + i * 2048 + w * 512;   // linear dest: base + lane*16B
      ushort* lpl = lAl + i * 2048 + w * 512;
      __builtin_amdgcn_global_load_lds((const __attribute__((address_space(1))) void*)gh,
                                       (__attribute__((address_space(3))) void*)lph, 16, 0, 0);
      __builtin_amdgcn_global_load_lds((const __attribute__((address_space(1))) void*)gl,
                                       (__attribute__((address_space(3))) void*)lpl, 16, 0, 0);
    }
    // stage B: wave w stages k-granule w, rows = lane
    {
      const ushort* gh = BH + (size_t)(bn + lane) * K + k0 + w * 8;
      const ushort* gl = BL + (size_t)(bn + lane) * K + k0 + w * 8;
      ushort* lph = lBh + w * 512;
      ushort* lpl = lBl + w * 512;
      __builtin_amdgcn_global_load_lds((const __attribute__((address_space(1))) void*)gh,
                                       (__attribute__((address_space(3))) void*)lph, 16, 0, 0);
      __builtin_amdgcn_global_load_lds((const __attribute__((address_space(1))) void*)gl,
                                       (__attribute__((address_space(3))) void*)lpl, 16, 0, 0);
    }
    __syncthreads();
    short8v ah[4], al[4], bh[4], bl[4];
    const int kg = lane >> 4;          // k-granule 0..3
    const int mrow = lane & 15;
    #pragma unroll
    for (int m = 0; m < 4; m++){
      ah[m] = *(const short8v*)(lAh + kg * 2048 + (w * 64 + m * 16 + mrow) * 8);
      al[m] = *(const short8v*)(lAl + kg * 2048 + (w * 64 + m * 16 + mrow) * 8);
    }
    #pragma unroll
    for (int n = 0; n < 4; n++){
      bh[n] = *(const short8v*)(lBh + kg * 512 + (n * 16 + mrow) * 8);
      bl[n] = *(const short8v*)(lBl + kg * 512 + (n * 16 + mrow) * 8);
    }
    #pragma unroll
    for (int m = 0; m < 4; m++)
      #pragma unroll
      for (int n = 0; n < 4; n++){
        acc[m][n] = __builtin_amdgcn_mfma_f32_16x16x32_bf16(al[m], bh[n], acc[m][n], 0, 0, 0);
        acc[m][n] = __builtin_amdgcn_mfma_f32_16x16x32_bf16(ah[m], bl[n], acc[m][n], 0, 0, 0);
        acc[m][n] = __builtin_amdgcn_mfma_f32_16x16x32_bf16(ah[m], bh[n], acc[m][n], 0, 0, 0);
      }
    __syncthreads();
  }

  float s1[4], s2[4];
  #pragma unroll
  for (int n = 0; n < 4; n++){ s1[n] = 0.f; s2[n] = 0.f; }

  const size_t rbase = bm + w * 64 + ((lane >> 4) * 4);
  #pragma unroll
  for (int n = 0; n < 4; n++){
    int c = bn + n * 16 + (lane & 15);
    float bv = bias[c];
    #pragma unroll
    for (int m = 0; m < 4; m++){
      #pragma unroll
      for (int j = 0; j < 4; j++){
        size_t r = rbase + m * 16 + j;
        float v = acc[m][n][j] + bv;
        if (RELU) v = fmaxf(v, 0.f);
        if (OUTSPLIT){
          ushort hi = f2bf(v);
          outh[r * LDC + c] = hi;
          outl[r * LDC + c] = f2bf(v - bf2f(hi));
        }
        if (STATS){
          outf[r * LDC + c] = v;
          outz[r * LDC + c] = f2bf(v);
          if (r < (size_t)Nrows){ s1[n] += v; s2[n] += v * v; }
        }
      }
    }
  }

  if (STATS){
    __shared__ float sred[2][64];
    if (tid < 64){ sred[0][tid] = 0.f; sred[1][tid] = 0.f; }
    __syncthreads();
    #pragma unroll
    for (int n = 0; n < 4; n++){
      float a = s1[n], b = s2[n];
      a += __shfl_xor(a, 16, 64); b += __shfl_xor(b, 16, 64);
      a += __shfl_xor(a, 32, 64); b += __shfl_xor(b, 32, 64);
      if (lane < 16){
        atomicAdd(&sred[0][n * 16 + lane], a);
        atomicAdd(&sred[1][n * 16 + lane], b);
      }
    }
    __syncthreads();
    if (tid < 64){
      atomicAdd(&bnacc[bn + tid], sred[0][tid]);
      atomicAdd(&bnacc[D1 + bn + tid], sred[1][tid]);
    }
  }
}

// ---------------- batch norm finalize ----------------
__global__ void k_bnfin(const float* __restrict__ accu, const float* __restrict__ gp,
                        const float* __restrict__ bp, int l, float* __restrict__ scsh, int N){
  int c = threadIdx.x;
  if (c >= D1) return;
  float invN = 1.0f / (float)N;
  float mu = accu[c] * invN;
  float var = accu[D1 + c] * invN - mu * mu;
  var = fmaxf(var, 0.f);
  float sc = gp[l * D1 + c] * rsqrtf(var + 1e-5f);
  scsh[c] = sc;
  scsh[D1 + c] = bp[l * D1 + c] - mu * sc;
}

// ---------------- readout: per-graph mean of BN(z) (graph_ids sorted; affine after mean) ------
__device__ __forceinline__ int lbound(const int* a, int n, int v){
  int lo = 0, hi = n;
  while (lo < hi){
    int mid = (lo + hi) >> 1;
    if (a[mid] < v) lo = mid + 1; else hi = mid;
  }
  return lo;
}
__global__ __launch_bounds__(128) void k_readout(const float* __restrict__ z,
                                                 const float* __restrict__ scsh,
                                                 const int* __restrict__ gid,
                                                 float* __restrict__ out, int N){
  int g = blockIdx.x;
  int t = threadIdx.x;
  if (t >= 75) return;  // 75*4 = 300 cols
  int s = lbound(gid, N, g);
  int e = lbound(gid, N, g + 1);
  float a0 = 0.f, a1 = 0.f, a2 = 0.f, a3 = 0.f;
  int r = s;
  for (; r + 2 <= e; r += 2){
    float4 v0 = *(const float4*)(z + (size_t)r * D1 + t * 4);
    float4 v1 = *(const float4*)(z + (size_t)(r + 1) * D1 + t * 4);
    a0 += v0.x + v1.x; a1 += v0.y + v1.y; a2 += v0.z + v1.z; a3 += v0.w + v1.w;
  }
  if (r < e){
    float4 v = *(const float4*)(z + (size_t)r * D1 + t * 4);
    a0 += v.x; a1 += v.y; a2 += v.z; a3 += v.w;
  }
  int c = t * 4;
  int cnt = e - s;
  if (cnt <= 0){
    out[(size_t)g * EMB + c + 0] = 0.f;
    out[(size_t)g * EMB + c + 1] = 0.f;
    out[(size_t)g * EMB + c + 2] = 0.f;
    out[(size_t)g * EMB + c + 3] = 0.f;
    return;
  }
  float inv = 1.0f / (float)cnt;
  float4 sc = *(const float4*)(scsh + c);
  float4 sh = *(const float4*)(scsh + D1 + c);
  out[(size_t)g * EMB + c + 0] = fmaf(a0 * inv, sc.x, sh.x);
  out[(size_t)g * EMB + c + 1] = fmaf(a1 * inv, sc.y, sh.y);
  out[(size_t)g * EMB + c + 2] = fmaf(a2 * inv, sc.z, sh.z);
  out[(size_t)g * EMB + c + 3] = fmaf(a3 * inv, sc.w, sh.w);
}

// ---------------- launch ----------------
extern "C" void kernel_launch(void* const* d_in, const int* in_sizes, int n_in,
                              void* d_out, int out_size, void* d_ws, size_t ws_size,
                              hipStream_t stream){
  const float* node_feats = (const float*)d_in[0];
  const float* W1    = (const float*)d_in[1];
  const float* b1    = (const float*)d_in[2];
  const float* W2    = (const float*)d_in[3];
  const float* b2    = (const float*)d_in[4];
  const float* eps   = (const float*)d_in[5];
  const float* gamma = (const float*)d_in[6];
  const float* beta  = (const float*)d_in[7];
  const int* src = (const int*)d_in[8];
  const int* dst = (const int*)d_in[9];
  const int* gid = (const int*)d_in[10];

  const int N = in_sizes[0] / EMB;
  const int E = in_sizes[8];
  const int G = out_size / EMB;
  const int MPAD = ((N + 255) / 256) * 256;

  char* ws = (char*)d_ws;
  // 3 segments of seg = MPAD*D1*4 B (= MPAD*D2*2 B). Roles rotate per layer:
  //   zin  = (l odd) ? S1 : S0     (read by fused aggregate, f32 self term)
  //   xseg = (l odd) ? S0 : S1     (xh | xl halves; x live agg->gemm1)
  //   yh -> zin seg (zin dead after agg), yl -> S2   (y live gemm1->gemm2)
  //   zout = xseg                  (x dead after gemm1)
  // zbf (bf16 z copy for the gather): own buffer, written gemm2(l)/hinit, read agg(l+1).
  const size_t seg = (size_t)MPAD * D1 * 4;
  char* S0 = ws;
  char* S1 = ws + seg;
  char* S2 = ws + 2 * seg;

  size_t off = 3 * seg;
  auto alloc = [&](size_t b){ size_t o = off; off += (b + 255) & ~(size_t)255; return o; };
  ushort* zbf  = (ushort*)(ws + alloc((size_t)MPAD * D1 * 2));
  ushort* w1h  = (ushort*)(ws + alloc((size_t)NLAYER * D2 * D1 * 2));
  ushort* w1l  = (ushort*)(ws + alloc((size_t)NLAYER * D2 * D1 * 2));
  ushort* w2h  = (ushort*)(ws + alloc((size_t)NLAYER * D1 * D2 * 2));
  ushort* w2l  = (ushort*)(ws + alloc((size_t)NLAYER * D1 * D2 * 2));
  float* b1p = (float*)(ws + alloc(NLAYER * D2 * 4));
  float* b2p = (float*)(ws + alloc(NLAYER * D1 * 4));
  float* gp  = (float*)(ws + alloc(NLAYER * D1 * 4));
  float* bp  = (float*)(ws + alloc(NLAYER * D1 * 4));
  int* deg     = (int*)(ws + alloc((size_t)N * 4));
  int* row_ptr = (int*)(ws + alloc((size_t)(N + 1) * 4));
  int* cursor  = (int*)(ws + alloc((size_t)N * 4));
  int* ssrc    = (int*)(ws + alloc((size_t)E * 4));
  float* bnacc = (float*)(ws + alloc(2 * D1 * 4));
  float* scsh  = (float*)(ws + alloc(2 * D1 * 4));
  float* scsh0 = (float*)(ws + alloc(2 * D1 * 4));

  k_prep_w1<<<(NLAYER * D2 * D1 + 255) / 256, 256, 0, stream>>>(W1, w1h, w1l);
  k_prep_w2<<<(NLAYER * D1 * D2 + 255) / 256, 256, 0, stream>>>(W2, w2h, w2l);
  k_prep_vec<<<(NLAYER * D2 + 255) / 256, 256, 0, stream>>>(b1, b2, gamma, beta,
                                                            b1p, b2p, gp, bp, scsh0);
  k_hinit<<<((size_t)N * 80 + 255) / 256, 256, 0, stream>>>(node_feats, (float*)S0, zbf, N);

  hipMemsetAsync(deg, 0, (size_t)N * 4, stream);
  k_count<<<(E + 255) / 256, 256, 0, stream>>>(dst, deg, E);
  k_scan<<<1, 1024, 0, stream>>>(deg, row_ptr, cursor, N);
  k_scatter<<<(E + 255) / 256, 256, 0, stream>>>(src, dst, cursor, ssrc, E);

  for (int l = 0; l < NLAYER; l++){
    char* zin  = (l & 1) ? S1 : S0;
    char* xsg  = (l & 1) ? S0 : S1;
    ushort* xh = (ushort*)xsg;
    ushort* xl = xh + (size_t)MPAD * D1;
    ushort* yh = (ushort*)zin;
    ushort* yl = (ushort*)S2;
    float* zout = (float*)xsg;
    const float* scin = (l == 0) ? scsh0 : scsh;

    k_aggregate<<<(N + 7) / 8, 320, 0, stream>>>((const float*)zin, zbf, scin, xh, xl,
                                                 row_ptr, ssrc, eps, l, (l > 0) ? 1 : 0, N);
    k_gemm<D1, D2, D2/64, true, true, false><<<(MPAD / 256) * (D2 / 64), 256, 0, stream>>>(
        xh, xl, w1h + (size_t)l * D2 * D1, w1l + (size_t)l * D2 * D1,
        b1p + l * D2, yh, yl, nullptr, nullptr, nullptr, 0);
    hipMemsetAsync(bnacc, 0, 2 * D1 * 4, stream);
    k_gemm<D2, D1, D1/64, false, false, true><<<(MPAD / 256) * (D1 / 64), 256, 0, stream>>>(
        yh, yl, w2h + (size_t)l * D1 * D2, w2l + (size_t)l * D1 * D2,
        b2p + l * D1, nullptr, nullptr, zout, zbf, bnacc, N);
    k_bnfin<<<1, D1, 0, stream>>>(bnacc, gp, bp, l, scsh, N);
  }
  // final z is in xseg of layer 4 = S1
  k_readout<<<G, 128, 0, stream>>>((const float*)S1, scsh, gid, (float*)d_out, N);
}

// Round 8
// 1642.718 us; speedup vs baseline: 1.6722x; 1.6722x over previous
//
#include <hip/hip_runtime.h>
#include <hip/hip_bf16.h>
#include <stdint.h>

#define EMB 300
#define D1 320      // padded EMB  (mult of 32)
#define D2 640      // padded 2*EMB (mult of 32)
#define NLAYER 5

typedef __attribute__((ext_vector_type(8))) short short8v;
typedef __attribute__((ext_vector_type(4))) float f32x4;

__device__ __forceinline__ float bf2f(ushort u){
  union { uint32_t i; float f; } c; c.i = ((uint32_t)u) << 16; return c.f;
}
__device__ __forceinline__ ushort f2bf(float f){
  union { float f; uint32_t i; } c; c.f = f;
  uint32_t i = c.i;
  return (ushort)((i + 0x7FFFu + ((i >> 16) & 1u)) >> 16);
}

// ---------------- weight prep: transpose + pad + bf16 split (hi + lo residual) ----------------
__global__ void k_prep_w1(const float* __restrict__ W1, ushort* __restrict__ W1H,
                          ushort* __restrict__ W1L){
  int id = blockIdx.x * 256 + threadIdx.x;
  if (id >= NLAYER * D2 * D1) return;
  int l = id / (D2 * D1), r = id % (D2 * D1);
  int n = r / D1, k = r % D1;   // W1T[l][n][k] = W1[l][k][n]
  float v = (n < 2*EMB && k < EMB) ? W1[((size_t)l * EMB + k) * (2*EMB) + n] : 0.f;
  ushort hi = f2bf(v);
  W1H[id] = hi;
  W1L[id] = f2bf(v - bf2f(hi));
}
__global__ void k_prep_w2(const float* __restrict__ W2, ushort* __restrict__ W2H,
                          ushort* __restrict__ W2L){
  int id = blockIdx.x * 256 + threadIdx.x;
  if (id >= NLAYER * D1 * D2) return;
  int l = id / (D1 * D2), r = id % (D1 * D2);
  int n = r / D2, k = r % D2;   // W2T[l][n][k] = W2[l][k][n]
  float v = (n < EMB && k < 2*EMB) ? W2[((size_t)l * (2*EMB) + k) * EMB + n] : 0.f;
  ushort hi = f2bf(v);
  W2H[id] = hi;
  W2L[id] = f2bf(v - bf2f(hi));
}
__global__ void k_prep_vec(const float* b1, const float* b2, const float* gamma, const float* beta,
                           float* b1p, float* b2p, float* gp, float* bp, float* scsh0){
  int id = blockIdx.x * 256 + threadIdx.x;
  if (id < NLAYER * D2){
    int l = id / D2, n = id % D2;
    b1p[id] = (n < 2*EMB) ? b1[l * (2*EMB) + n] : 0.f;
  }
  if (id < NLAYER * D1){
    int l = id / D1, c = id % D1;
    b2p[id] = (c < EMB) ? b2[l * EMB + c]    : 0.f;
    gp[id]  = (c < EMB) ? gamma[l * EMB + c] : 0.f;
    bp[id]  = (c < EMB) ? beta[l * EMB + c]  : 0.f;
  }
  if (id < D1){                 // identity affine for layer 0's fused "BN"
    scsh0[id] = 1.0f;
    scsh0[D1 + id] = 0.0f;
  }
}
// initial z0 (f32 padded) + bf16 copy for the gather
__global__ void k_hinit(const float* __restrict__ nf, float* __restrict__ z,
                        ushort* __restrict__ zbf, int N){
  int id = blockIdx.x * 256 + threadIdx.x;
  if (id >= N * 80) return;
  int n = id / 80, q = id % 80;
  float4 v = make_float4(0.f, 0.f, 0.f, 0.f);
  if (q < 75) v = *(const float4*)(nf + (size_t)n * EMB + q * 4);  // 300 = 75*4
  *(float4*)(z + (size_t)n * D1 + q * 4) = v;
  ushort o[4] = {f2bf(v.x), f2bf(v.y), f2bf(v.z), f2bf(v.w)};
  *(uint2*)(zbf + (size_t)n * D1 + q * 4) = *(const uint2*)o;
}

// ---------------- CSR build (counting sort by dst) ----------------
__global__ void k_count(const int* __restrict__ dst, int* __restrict__ deg, int E){
  int e = blockIdx.x * 256 + threadIdx.x;
  if (e < E) atomicAdd(&deg[dst[e]], 1);
}
__global__ __launch_bounds__(1024) void k_scan(const int* __restrict__ deg,
                                               int* __restrict__ row_ptr,
                                               int* __restrict__ cursor, int N){
  __shared__ int wsum[16];
  __shared__ int carryS;
  int tid = threadIdx.x, lane = tid & 63, wid = tid >> 6;
  if (tid == 0) carryS = 0;
  __syncthreads();
  for (int base = 0; base < N; base += 1024){
    int i = base + tid;
    int v = (i < N) ? deg[i] : 0;
    int isc = v;
    #pragma unroll
    for (int off = 1; off < 64; off <<= 1){
      int t = __shfl_up(isc, off, 64);
      if (lane >= off) isc += t;
    }
    if (lane == 63) wsum[wid] = isc;
    __syncthreads();
    int woff = 0;
    for (int ww = 0; ww < wid; ww++) woff += wsum[ww];
    int carry = carryS;
    int excl = carry + woff + isc - v;
    if (i < N){ row_ptr[i] = excl; cursor[i] = excl; }
    __syncthreads();
    if (tid == 0){
      int s = 0;
      for (int ww = 0; ww < 16; ww++) s += wsum[ww];
      carryS = carry + s;
    }
    __syncthreads();
  }
  if (tid == 0) row_ptr[N] = carryS;
}
__global__ void k_scatter(const int* __restrict__ src, const int* __restrict__ dst,
                          int* __restrict__ cursor, int* __restrict__ ssrc, int E){
  int e = blockIdx.x * 256 + threadIdx.x;
  if (e < E){
    int p = atomicAdd(&cursor[dst[e]], 1);
    ssrc[p] = src[e];
  }
}

// ---------------- fused BN-apply + aggregation ----------------
// self term: exact f32 z; neighbor term: bf16 copy zbf (half the gather bytes).
// h = relu?(val*sc + sh); x = (1+eps)h_self + sum_neigh h[src].
// block = 320 threads = 8 nodes x 40 chunks (8 cols each)
__global__ __launch_bounds__(320) void k_aggregate(const float* __restrict__ z,
                                                   const ushort* __restrict__ zbf,
                                                   const float* __restrict__ scsh,
                                                   ushort* __restrict__ xh,
                                                   ushort* __restrict__ xl,
                                                   const int* __restrict__ row_ptr,
                                                   const int* __restrict__ ssrc,
                                                   const float* __restrict__ eps,
                                                   int l, int relu, int N){
  int t = threadIdx.x;
  int nl = t / 40, q = t % 40;
  int n = blockIdx.x * 8 + nl;
  if (n >= N) return;
  const int c0 = q * 8;
  float sc[8], sh[8];
  {
    float4 a = *(const float4*)(scsh + c0);
    float4 b = *(const float4*)(scsh + c0 + 4);
    float4 c = *(const float4*)(scsh + D1 + c0);
    float4 d = *(const float4*)(scsh + D1 + c0 + 4);
    sc[0]=a.x; sc[1]=a.y; sc[2]=a.z; sc[3]=a.w; sc[4]=b.x; sc[5]=b.y; sc[6]=b.z; sc[7]=b.w;
    sh[0]=c.x; sh[1]=c.y; sh[2]=c.z; sh[3]=c.w; sh[4]=d.x; sh[5]=d.y; sh[6]=d.z; sh[7]=d.w;
  }
  float acc[8];
  {
    const float* zp = z + (size_t)n * D1 + c0;
    float4 a = *(const float4*)zp, b = *(const float4*)(zp + 4);
    float v[8] = {a.x,a.y,a.z,a.w,b.x,b.y,b.z,b.w};
    float se = 1.0f + eps[l];
    #pragma unroll
    for (int j = 0; j < 8; j++){
      float u = fmaf(v[j], sc[j], sh[j]);
      if (relu) u = fmaxf(u, 0.f);
      acc[j] = se * u;
    }
  }
  auto accrow = [&](uint4 u){
    const ushort* us = (const ushort*)&u;
    #pragma unroll
    for (int j = 0; j < 8; j++){
      float x = fmaf(bf2f(us[j]), sc[j], sh[j]);
      if (relu) x = fmaxf(x, 0.f);
      acc[j] += x;
    }
  };
  int e0 = row_ptr[n], e1 = row_ptr[n + 1];
  int e = e0;
  for (; e + 4 <= e1; e += 4){
    int s0 = ssrc[e], s1 = ssrc[e+1], s2 = ssrc[e+2], s3 = ssrc[e+3];
    uint4 u0 = *(const uint4*)(zbf + (size_t)s0 * D1 + c0);
    uint4 u1 = *(const uint4*)(zbf + (size_t)s1 * D1 + c0);
    uint4 u2 = *(const uint4*)(zbf + (size_t)s2 * D1 + c0);
    uint4 u3 = *(const uint4*)(zbf + (size_t)s3 * D1 + c0);
    accrow(u0); accrow(u1); accrow(u2); accrow(u3);
  }
  for (; e < e1; e++){
    uint4 u = *(const uint4*)(zbf + (size_t)ssrc[e] * D1 + c0);
    accrow(u);
  }
  ushort oh[8], ol[8];
  #pragma unroll
  for (int j = 0; j < 8; j++){
    oh[j] = f2bf(acc[j]);
    ol[j] = f2bf(acc[j] - bf2f(oh[j]));
  }
  *(uint4*)(xh + (size_t)n * D1 + q * 8) = *(const uint4*)oh;
  *(uint4*)(xl + (size_t)n * D1 + q * 8) = *(const uint4*)ol;
}

// ---------------- GEMM: C = (AH+AL)[MPAD x K] * (BH+BL)[K x LDC] (+bias, relu) ----------------
// B is transposed [LDC][K]. acc += Ah*Bh + Al*Bh + Ah*Bl (Al*Bl dropped, ~2^-16 rel).
// Tile 256x64, BK=32, 4 waves on M. 1-D grid, bijective XCD-chunked (m,n) decode (T1+m204).
// LDS tiles row-major [row][32] with XOR GRANULE SWIZZLE (rule 21, both sides):
//   slot (row, g') holds global granule g = g' ^ ((row&15)>>2).
//   Staging keeps round-6 coalescing (4 lanes cover one 64B row segment, permuted);
//   fragment ds_read_b128 hits 8 distinct 16B bank slots x 2 lanes = 2-way = free.
// STATS: per-column sum/sumsq into bnacc + f32 z AND bf16 z copy (outz) for the next gather.
template<int K, int LDC, int NBN, bool RELU, bool OUTSPLIT, bool STATS>
__global__ __launch_bounds__(256) void k_gemm(const ushort* __restrict__ AH,
                                              const ushort* __restrict__ AL,
                                              const ushort* __restrict__ BH,
                                              const ushort* __restrict__ BL,
                                              const float* __restrict__ bias,
                                              ushort* __restrict__ outh,
                                              ushort* __restrict__ outl,
                                              float* __restrict__ outf,
                                              ushort* __restrict__ outz,
                                              float* __restrict__ bnacc,
                                              int Nrows){
  __shared__ ushort smem[2 * 256 * 32 + 2 * 64 * 32];
  const int tid = threadIdx.x;
  const int lane = tid & 63;
  const int w = tid >> 6;

  const int nwg = gridDim.x;
  const int q8 = nwg >> 3, r8 = nwg & 7;
  const int xcd = blockIdx.x & 7, pos = blockIdx.x >> 3;
  const int wg = (xcd < r8 ? xcd * (q8 + 1) : r8 * (q8 + 1) + (xcd - r8) * q8) + pos;
  const size_t bm = (size_t)(wg / NBN) * 256;
  const int bn = (wg % NBN) * 64;

  f32x4 acc[4][4];
  #pragma unroll
  for (int m = 0; m < 4; m++)
    #pragma unroll
    for (int n = 0; n < 4; n++)
      acc[m][n] = f32x4{0.f, 0.f, 0.f, 0.f};

  ushort* lAh = smem;
  ushort* lAl = smem + 256 * 32;
  ushort* lBh = smem + 2 * 256 * 32;
  ushort* lBl = smem + 2 * 256 * 32 + 64 * 32;
  const int rsub = lane >> 2;                        // 0..15 rows within a 16-row stripe
  const int gsw  = (lane & 3) ^ ((lane >> 4) & 3);   // swizzled global granule for staging
  const int csub = gsw * 8;                          // k-element offset (16B granule)

  for (int k0 = 0; k0 < K; k0 += 32){
    // stage A tile (256x32): 4 issues x 4 waves x 16 rows, coalesced per 64B row segment
    #pragma unroll
    for (int i = 0; i < 4; i++){
      int r = i * 64 + w * 16 + rsub;
      const ushort* gh = AH + (bm + r) * K + k0 + csub;
      const ushort* gl = AL + (bm + r) * K + k0 + csub;
      ushort* lph = lAh + (i * 64 + w * 16) * 32;   // wave-uniform base; HW adds lane*16B
      ushort* lpl = lAl + (i * 64 + w * 16) * 32;
      __builtin_amdgcn_global_load_lds((const __attribute__((address_space(1))) void*)gh,
                                       (__attribute__((address_space(3))) void*)lph, 16, 0, 0);
      __builtin_amdgcn_global_load_lds((const __attribute__((address_space(1))) void*)gl,
                                       (__attribute__((address_space(3))) void*)lpl, 16, 0, 0);
    }
    // stage B tiles (64x32 each)
    {
      int r = w * 16 + rsub;
      const ushort* gh = BH + (size_t)(bn + r) * K + k0 + csub;
      const ushort* gl = BL + (size_t)(bn + r) * K + k0 + csub;
      ushort* lph = lBh + (w * 16) * 32;
      ushort* lpl = lBl + (w * 16) * 32;
      __builtin_amdgcn_global_load_lds((const __attribute__((address_space(1))) void*)gh,
                                       (__attribute__((address_space(3))) void*)lph, 16, 0, 0);
      __builtin_amdgcn_global_load_lds((const __attribute__((address_space(1))) void*)gl,
                                       (__attribute__((address_space(3))) void*)lpl, 16, 0, 0);
    }
    __syncthreads();
    short8v ah[4], al[4], bh[4], bl[4];
    const int kg = lane >> 4;          // wanted k-granule 0..3
    const int mrow = lane & 15;
    const int krow = (kg ^ (mrow >> 2)) * 8;   // swizzled slot
    #pragma unroll
    for (int m = 0; m < 4; m++){
      ah[m] = *(const short8v*)(lAh + (w * 64 + m * 16 + mrow) * 32 + krow);
      al[m] = *(const short8v*)(lAl + (w * 64 + m * 16 + mrow) * 32 + krow);
    }
    #pragma unroll
    for (int n = 0; n < 4; n++){
      bh[n] = *(const short8v*)(lBh + (n * 16 + mrow) * 32 + krow);
      bl[n] = *(const short8v*)(lBl + (n * 16 + mrow) * 32 + krow);
    }
    #pragma unroll
    for (int m = 0; m < 4; m++)
      #pragma unroll
      for (int n = 0; n < 4; n++){
        acc[m][n] = __builtin_amdgcn_mfma_f32_16x16x32_bf16(al[m], bh[n], acc[m][n], 0, 0, 0);
        acc[m][n] = __builtin_amdgcn_mfma_f32_16x16x32_bf16(ah[m], bl[n], acc[m][n], 0, 0, 0);
        acc[m][n] = __builtin_amdgcn_mfma_f32_16x16x32_bf16(ah[m], bh[n], acc[m][n], 0, 0, 0);
      }
    __syncthreads();
  }

  float s1[4], s2[4];
  #pragma unroll
  for (int n = 0; n < 4; n++){ s1[n] = 0.f; s2[n] = 0.f; }

  const size_t rbase = bm + w * 64 + ((lane >> 4) * 4);
  #pragma unroll
  for (int n = 0; n < 4; n++){
    int c = bn + n * 16 + (lane & 15);
    float bv = bias[c];
    #pragma unroll
    for (int m = 0; m < 4; m++){
      #pragma unroll
      for (int j = 0; j < 4; j++){
        size_t r = rbase + m * 16 + j;
        float v = acc[m][n][j] + bv;
        if (RELU) v = fmaxf(v, 0.f);
        if (OUTSPLIT){
          ushort hi = f2bf(v);
          outh[r * LDC + c] = hi;
          outl[r * LDC + c] = f2bf(v - bf2f(hi));
        }
        if (STATS){
          outf[r * LDC + c] = v;
          outz[r * LDC + c] = f2bf(v);
          if (r < (size_t)Nrows){ s1[n] += v; s2[n] += v * v; }
        }
      }
    }
  }

  if (STATS){
    __shared__ float sred[2][64];
    if (tid < 64){ sred[0][tid] = 0.f; sred[1][tid] = 0.f; }
    __syncthreads();
    #pragma unroll
    for (int n = 0; n < 4; n++){
      float a = s1[n], b = s2[n];
      a += __shfl_xor(a, 16, 64); b += __shfl_xor(b, 16, 64);
      a += __shfl_xor(a, 32, 64); b += __shfl_xor(b, 32, 64);
      if (lane < 16){
        atomicAdd(&sred[0][n * 16 + lane], a);
        atomicAdd(&sred[1][n * 16 + lane], b);
      }
    }
    __syncthreads();
    if (tid < 64){
      atomicAdd(&bnacc[bn + tid], sred[0][tid]);
      atomicAdd(&bnacc[D1 + bn + tid], sred[1][tid]);
    }
  }
}

// ---------------- batch norm finalize ----------------
__global__ void k_bnfin(const float* __restrict__ accu, const float* __restrict__ gp,
                        const float* __restrict__ bp, int l, float* __restrict__ scsh, int N){
  int c = threadIdx.x;
  if (c >= D1) return;
  float invN = 1.0f / (float)N;
  float mu = accu[c] * invN;
  float var = accu[D1 + c] * invN - mu * mu;
  var = fmaxf(var, 0.f);
  float sc = gp[l * D1 + c] * rsqrtf(var + 1e-5f);
  scsh[c] = sc;
  scsh[D1 + c] = bp[l * D1 + c] - mu * sc;
}

// ---------------- readout: per-graph mean of BN(z) (graph_ids sorted; affine after mean) ------
__device__ __forceinline__ int lbound(const int* a, int n, int v){
  int lo = 0, hi = n;
  while (lo < hi){
    int mid = (lo + hi) >> 1;
    if (a[mid] < v) lo = mid + 1; else hi = mid;
  }
  return lo;
}
__global__ __launch_bounds__(128) void k_readout(const float* __restrict__ z,
                                                 const float* __restrict__ scsh,
                                                 const int* __restrict__ gid,
                                                 float* __restrict__ out, int N){
  int g = blockIdx.x;
  int t = threadIdx.x;
  if (t >= 75) return;  // 75*4 = 300 cols
  int s = lbound(gid, N, g);
  int e = lbound(gid, N, g + 1);
  float a0 = 0.f, a1 = 0.f, a2 = 0.f, a3 = 0.f;
  int r = s;
  for (; r + 2 <= e; r += 2){
    float4 v0 = *(const float4*)(z + (size_t)r * D1 + t * 4);
    float4 v1 = *(const float4*)(z + (size_t)(r + 1) * D1 + t * 4);
    a0 += v0.x + v1.x; a1 += v0.y + v1.y; a2 += v0.z + v1.z; a3 += v0.w + v1.w;
  }
  if (r < e){
    float4 v = *(const float4*)(z + (size_t)r * D1 + t * 4);
    a0 += v.x; a1 += v.y; a2 += v.z; a3 += v.w;
  }
  int c = t * 4;
  int cnt = e - s;
  if (cnt <= 0){
    out[(size_t)g * EMB + c + 0] = 0.f;
    out[(size_t)g * EMB + c + 1] = 0.f;
    out[(size_t)g * EMB + c + 2] = 0.f;
    out[(size_t)g * EMB + c + 3] = 0.f;
    return;
  }
  float inv = 1.0f / (float)cnt;
  float4 sc = *(const float4*)(scsh + c);
  float4 sh = *(const float4*)(scsh + D1 + c);
  out[(size_t)g * EMB + c + 0] = fmaf(a0 * inv, sc.x, sh.x);
  out[(size_t)g * EMB + c + 1] = fmaf(a1 * inv, sc.y, sh.y);
  out[(size_t)g * EMB + c + 2] = fmaf(a2 * inv, sc.z, sh.z);
  out[(size_t)g * EMB + c + 3] = fmaf(a3 * inv, sc.w, sh.w);
}

// ---------------- launch ----------------
extern "C" void kernel_launch(void* const* d_in, const int* in_sizes, int n_in,
                              void* d_out, int out_size, void* d_ws, size_t ws_size,
                              hipStream_t stream){
  const float* node_feats = (const float*)d_in[0];
  const float* W1    = (const float*)d_in[1];
  const float* b1    = (const float*)d_in[2];
  const float* W2    = (const float*)d_in[3];
  const float* b2    = (const float*)d_in[4];
  const float* eps   = (const float*)d_in[5];
  const float* gamma = (const float*)d_in[6];
  const float* beta  = (const float*)d_in[7];
  const int* src = (const int*)d_in[8];
  const int* dst = (const int*)d_in[9];
  const int* gid = (const int*)d_in[10];

  const int N = in_sizes[0] / EMB;
  const int E = in_sizes[8];
  const int G = out_size / EMB;
  const int MPAD = ((N + 255) / 256) * 256;

  char* ws = (char*)d_ws;
  // 3 segments of seg = MPAD*D1*4 B (= MPAD*D2*2 B). Roles rotate per layer:
  //   zin  = (l odd) ? S1 : S0     (read by fused aggregate, f32 self term)
  //   xseg = (l odd) ? S0 : S1     (xh | xl halves; x live agg->gemm1)
  //   yh -> zin seg (zin dead after agg), yl -> S2   (y live gemm1->gemm2)
  //   zout = xseg                  (x dead after gemm1)
  // zbf (bf16 z copy for the gather): own buffer, written gemm2(l)/hinit, read agg(l+1).
  const size_t seg = (size_t)MPAD * D1 * 4;
  char* S0 = ws;
  char* S1 = ws + seg;
  char* S2 = ws + 2 * seg;

  size_t off = 3 * seg;
  auto alloc = [&](size_t b){ size_t o = off; off += (b + 255) & ~(size_t)255; return o; };
  ushort* zbf  = (ushort*)(ws + alloc((size_t)MPAD * D1 * 2));
  ushort* w1h  = (ushort*)(ws + alloc((size_t)NLAYER * D2 * D1 * 2));
  ushort* w1l  = (ushort*)(ws + alloc((size_t)NLAYER * D2 * D1 * 2));
  ushort* w2h  = (ushort*)(ws + alloc((size_t)NLAYER * D1 * D2 * 2));
  ushort* w2l  = (ushort*)(ws + alloc((size_t)NLAYER * D1 * D2 * 2));
  float* b1p = (float*)(ws + alloc(NLAYER * D2 * 4));
  float* b2p = (float*)(ws + alloc(NLAYER * D1 * 4));
  float* gp  = (float*)(ws + alloc(NLAYER * D1 * 4));
  float* bp  = (float*)(ws + alloc(NLAYER * D1 * 4));
  int* deg     = (int*)(ws + alloc((size_t)N * 4));
  int* row_ptr = (int*)(ws + alloc((size_t)(N + 1) * 4));
  int* cursor  = (int*)(ws + alloc((size_t)N * 4));
  int* ssrc    = (int*)(ws + alloc((size_t)E * 4));
  float* bnacc = (float*)(ws + alloc(2 * D1 * 4));
  float* scsh  = (float*)(ws + alloc(2 * D1 * 4));
  float* scsh0 = (float*)(ws + alloc(2 * D1 * 4));

  k_prep_w1<<<(NLAYER * D2 * D1 + 255) / 256, 256, 0, stream>>>(W1, w1h, w1l);
  k_prep_w2<<<(NLAYER * D1 * D2 + 255) / 256, 256, 0, stream>>>(W2, w2h, w2l);
  k_prep_vec<<<(NLAYER * D2 + 255) / 256, 256, 0, stream>>>(b1, b2, gamma, beta,
                                                            b1p, b2p, gp, bp, scsh0);
  k_hinit<<<((size_t)N * 80 + 255) / 256, 256, 0, stream>>>(node_feats, (float*)S0, zbf, N);

  hipMemsetAsync(deg, 0, (size_t)N * 4, stream);
  k_count<<<(E + 255) / 256, 256, 0, stream>>>(dst, deg, E);
  k_scan<<<1, 1024, 0, stream>>>(deg, row_ptr, cursor, N);
  k_scatter<<<(E + 255) / 256, 256, 0, stream>>>(src, dst, cursor, ssrc, E);

  for (int l = 0; l < NLAYER; l++){
    char* zin  = (l & 1) ? S1 : S0;
    char* xsg  = (l & 1) ? S0 : S1;
    ushort* xh = (ushort*)xsg;
    ushort* xl = xh + (size_t)MPAD * D1;
    ushort* yh = (ushort*)zin;
    ushort* yl = (ushort*)S2;
    float* zout = (float*)xsg;
    const float* scin = (l == 0) ? scsh0 : scsh;

    k_aggregate<<<(N + 7) / 8, 320, 0, stream>>>((const float*)zin, zbf, scin, xh, xl,
                                                 row_ptr, ssrc, eps, l, (l > 0) ? 1 : 0, N);
    k_gemm<D1, D2, D2/64, true, true, false><<<(MPAD / 256) * (D2 / 64), 256, 0, stream>>>(
        xh, xl, w1h + (size_t)l * D2 * D1, w1l + (size_t)l * D2 * D1,
        b1p + l * D2, yh, yl, nullptr, nullptr, nullptr, 0);
    hipMemsetAsync(bnacc, 0, 2 * D1 * 4, stream);
    k_gemm<D2, D1, D1/64, false, false, true><<<(MPAD / 256) * (D1 / 64), 256, 0, stream>>>(
        yh, yl, w2h + (size_t)l * D1 * D2, w2l + (size_t)l * D1 * D2,
        b2p + l * D1, nullptr, nullptr, zout, zbf, bnacc, N);
    k_bnfin<<<1, D1, 0, stream>>>(bnacc, gp, bp, l, scsh, N);
  }
  // final z is in xseg of layer 4 = S1
  k_readout<<<G, 128, 0, stream>>>((const float*)S1, scsh, gid, (float*)d_out, N);
}

// Round 9
// 1562.485 us; speedup vs baseline: 1.7581x; 1.0513x over previous
//
#include <hip/hip_runtime.h>
#include <hip/hip_bf16.h>
#include <stdint.h>

#define EMB 300
#define D1 320      // padded EMB  (mult of 32)
#define D2 640      // padded 2*EMB (mult of 32)
#define NLAYER 5

typedef __attribute__((ext_vector_type(8))) short short8v;
typedef __attribute__((ext_vector_type(4))) float f32x4;

__device__ __forceinline__ float bf2f(ushort u){
  union { uint32_t i; float f; } c; c.i = ((uint32_t)u) << 16; return c.f;
}
__device__ __forceinline__ ushort f2bf(float f){
  union { float f; uint32_t i; } c; c.f = f;
  uint32_t i = c.i;
  return (ushort)((i + 0x7FFFu + ((i >> 16) & 1u)) >> 16);
}

// ---------------- weight prep: transpose + pad + bf16 split (hi + lo residual) ----------------
__global__ void k_prep_w1(const float* __restrict__ W1, ushort* __restrict__ W1H,
                          ushort* __restrict__ W1L){
  int id = blockIdx.x * 256 + threadIdx.x;
  if (id >= NLAYER * D2 * D1) return;
  int l = id / (D2 * D1), r = id % (D2 * D1);
  int n = r / D1, k = r % D1;   // W1T[l][n][k] = W1[l][k][n]
  float v = (n < 2*EMB && k < EMB) ? W1[((size_t)l * EMB + k) * (2*EMB) + n] : 0.f;
  ushort hi = f2bf(v);
  W1H[id] = hi;
  W1L[id] = f2bf(v - bf2f(hi));
}
__global__ void k_prep_w2(const float* __restrict__ W2, ushort* __restrict__ W2H,
                          ushort* __restrict__ W2L){
  int id = blockIdx.x * 256 + threadIdx.x;
  if (id >= NLAYER * D1 * D2) return;
  int l = id / (D1 * D2), r = id % (D1 * D2);
  int n = r / D2, k = r % D2;   // W2T[l][n][k] = W2[l][k][n]
  float v = (n < EMB && k < 2*EMB) ? W2[((size_t)l * (2*EMB) + k) * EMB + n] : 0.f;
  ushort hi = f2bf(v);
  W2H[id] = hi;
  W2L[id] = f2bf(v - bf2f(hi));
}
__global__ void k_prep_vec(const float* b1, const float* b2, const float* gamma, const float* beta,
                           float* b1p, float* b2p, float* gp, float* bp, float* scsh0){
  int id = blockIdx.x * 256 + threadIdx.x;
  if (id < NLAYER * D2){
    int l = id / D2, n = id % D2;
    b1p[id] = (n < 2*EMB) ? b1[l * (2*EMB) + n] : 0.f;
  }
  if (id < NLAYER * D1){
    int l = id / D1, c = id % D1;
    b2p[id] = (c < EMB) ? b2[l * EMB + c]    : 0.f;
    gp[id]  = (c < EMB) ? gamma[l * EMB + c] : 0.f;
    bp[id]  = (c < EMB) ? beta[l * EMB + c]  : 0.f;
  }
  if (id < D1){                 // identity affine for layer 0's fused "BN"
    scsh0[id] = 1.0f;
    scsh0[D1 + id] = 0.0f;
  }
}
// initial z0 as bf16 hi/lo split planes
__global__ void k_hinit(const float* __restrict__ nf, ushort* __restrict__ zh,
                        ushort* __restrict__ zl, int N){
  int id = blockIdx.x * 256 + threadIdx.x;
  if (id >= N * 80) return;
  int n = id / 80, q = id % 80;
  float4 v = make_float4(0.f, 0.f, 0.f, 0.f);
  if (q < 75) v = *(const float4*)(nf + (size_t)n * EMB + q * 4);  // 300 = 75*4
  float vv[4] = {v.x, v.y, v.z, v.w};
  ushort hh[4], hl[4];
  #pragma unroll
  for (int j = 0; j < 4; j++){
    hh[j] = f2bf(vv[j]);
    hl[j] = f2bf(vv[j] - bf2f(hh[j]));
  }
  *(uint2*)(zh + (size_t)n * D1 + q * 4) = *(const uint2*)hh;
  *(uint2*)(zl + (size_t)n * D1 + q * 4) = *(const uint2*)hl;
}

// ---------------- CSR build (counting sort by dst) ----------------
__global__ void k_count(const int* __restrict__ dst, int* __restrict__ deg, int E){
  int e = blockIdx.x * 256 + threadIdx.x;
  if (e < E) atomicAdd(&deg[dst[e]], 1);
}
__global__ __launch_bounds__(1024) void k_scan(const int* __restrict__ deg,
                                               int* __restrict__ row_ptr,
                                               int* __restrict__ cursor, int N){
  __shared__ int wsum[16];
  __shared__ int carryS;
  int tid = threadIdx.x, lane = tid & 63, wid = tid >> 6;
  if (tid == 0) carryS = 0;
  __syncthreads();
  for (int base = 0; base < N; base += 1024){
    int i = base + tid;
    int v = (i < N) ? deg[i] : 0;
    int isc = v;
    #pragma unroll
    for (int off = 1; off < 64; off <<= 1){
      int t = __shfl_up(isc, off, 64);
      if (lane >= off) isc += t;
    }
    if (lane == 63) wsum[wid] = isc;
    __syncthreads();
    int woff = 0;
    for (int ww = 0; ww < wid; ww++) woff += wsum[ww];
    int carry = carryS;
    int excl = carry + woff + isc - v;
    if (i < N){ row_ptr[i] = excl; cursor[i] = excl; }
    __syncthreads();
    if (tid == 0){
      int s = 0;
      for (int ww = 0; ww < 16; ww++) s += wsum[ww];
      carryS = carry + s;
    }
    __syncthreads();
  }
  if (tid == 0) row_ptr[N] = carryS;
}
__global__ void k_scatter(const int* __restrict__ src, const int* __restrict__ dst,
                          int* __restrict__ cursor, int* __restrict__ ssrc, int E){
  int e = blockIdx.x * 256 + threadIdx.x;
  if (e < E){
    int p = atomicAdd(&cursor[dst[e]], 1);
    ssrc[p] = src[e];
  }
}

// ---------------- fused BN-apply + aggregation ----------------
// z stored as split bf16 planes zh/zl. Self term: zh+zl (~f32-exact). Neighbors: zh only.
// h = relu?(val*sc + sh); x = (1+eps)h_self + sum_neigh h[src].
// block = 320 threads = 8 nodes x 40 chunks (8 cols each)
__global__ __launch_bounds__(320) void k_aggregate(const ushort* __restrict__ zh,
                                                   const ushort* __restrict__ zl,
                                                   const float* __restrict__ scsh,
                                                   ushort* __restrict__ xh,
                                                   ushort* __restrict__ xl,
                                                   const int* __restrict__ row_ptr,
                                                   const int* __restrict__ ssrc,
                                                   const float* __restrict__ eps,
                                                   int l, int relu, int N){
  int t = threadIdx.x;
  int nl = t / 40, q = t % 40;
  int n = blockIdx.x * 8 + nl;
  if (n >= N) return;
  const int c0 = q * 8;
  float sc[8], sh[8];
  {
    float4 a = *(const float4*)(scsh + c0);
    float4 b = *(const float4*)(scsh + c0 + 4);
    float4 c = *(const float4*)(scsh + D1 + c0);
    float4 d = *(const float4*)(scsh + D1 + c0 + 4);
    sc[0]=a.x; sc[1]=a.y; sc[2]=a.z; sc[3]=a.w; sc[4]=b.x; sc[5]=b.y; sc[6]=b.z; sc[7]=b.w;
    sh[0]=c.x; sh[1]=c.y; sh[2]=c.z; sh[3]=c.w; sh[4]=d.x; sh[5]=d.y; sh[6]=d.z; sh[7]=d.w;
  }
  float acc[8];
  {
    uint4 uh = *(const uint4*)(zh + (size_t)n * D1 + c0);
    uint4 ul = *(const uint4*)(zl + (size_t)n * D1 + c0);
    const ushort* ph = (const ushort*)&uh;
    const ushort* pl = (const ushort*)&ul;
    float se = 1.0f + eps[l];
    #pragma unroll
    for (int j = 0; j < 8; j++){
      float v = bf2f(ph[j]) + bf2f(pl[j]);
      float u = fmaf(v, sc[j], sh[j]);
      if (relu) u = fmaxf(u, 0.f);
      acc[j] = se * u;
    }
  }
  auto accrow = [&](uint4 u){
    const ushort* us = (const ushort*)&u;
    #pragma unroll
    for (int j = 0; j < 8; j++){
      float x = fmaf(bf2f(us[j]), sc[j], sh[j]);
      if (relu) x = fmaxf(x, 0.f);
      acc[j] += x;
    }
  };
  int e0 = row_ptr[n], e1 = row_ptr[n + 1];
  int e = e0;
  for (; e + 4 <= e1; e += 4){
    int s0 = ssrc[e], s1 = ssrc[e+1], s2 = ssrc[e+2], s3 = ssrc[e+3];
    uint4 u0 = *(const uint4*)(zh + (size_t)s0 * D1 + c0);
    uint4 u1 = *(const uint4*)(zh + (size_t)s1 * D1 + c0);
    uint4 u2 = *(const uint4*)(zh + (size_t)s2 * D1 + c0);
    uint4 u3 = *(const uint4*)(zh + (size_t)s3 * D1 + c0);
    accrow(u0); accrow(u1); accrow(u2); accrow(u3);
  }
  for (; e < e1; e++){
    uint4 u = *(const uint4*)(zh + (size_t)ssrc[e] * D1 + c0);
    accrow(u);
  }
  ushort oh[8], ol[8];
  #pragma unroll
  for (int j = 0; j < 8; j++){
    oh[j] = f2bf(acc[j]);
    ol[j] = f2bf(acc[j] - bf2f(oh[j]));
  }
  *(uint4*)(xh + (size_t)n * D1 + q * 8) = *(const uint4*)oh;
  *(uint4*)(xl + (size_t)n * D1 + q * 8) = *(const uint4*)ol;
}

// ---------------- GEMM: C = (AH+AL)[MPAD x K] * (BH+BL)[K x LDC] (+bias, relu) ----------------
// B is transposed [LDC][K]. acc += Ah*Bh + Al*Bh + Ah*Bl (Al*Bl dropped, ~2^-16 rel).
// Tile 256x64, BK=32, 4 waves on M. 1-D grid, bijective XCD-chunked (m,n) decode (T1+m204).
// 2-PHASE DOUBLE-BUFFERED k-pipeline (T3-minimum): stage tile t+1 BEFORE consuming tile t,
// one barrier per k-step (its vmcnt drain lands after ds_read+MFMA -> latency hidden).
// LDS = 2 x 40KB buffers = 80KB (2 blocks/CU); stats scratch aliased into LDS post-loop.
// Per buffer (ushort offsets): lAh 0 (8192), lAl 8192, lBh 16384 (2048), lBl 18432.
// XOR granule swizzle kept from r8: slot g' = g ^ ((row&15)>>2) on both stage-src and read.
// Output always split bf16 hi/lo. STATS additionally accumulates per-col sum/sumsq (rows<Nrows).
template<int K, int LDC, int NBN, bool RELU, bool STATS>
__global__ __launch_bounds__(256) void k_gemm(const ushort* __restrict__ AH,
                                              const ushort* __restrict__ AL,
                                              const ushort* __restrict__ BH,
                                              const ushort* __restrict__ BL,
                                              const float* __restrict__ bias,
                                              ushort* __restrict__ outh,
                                              ushort* __restrict__ outl,
                                              float* __restrict__ bnacc,
                                              int Nrows){
  __shared__ ushort smem[2 * 20480];   // 80 KB
  const int tid = threadIdx.x;
  const int lane = tid & 63;
  const int w = tid >> 6;

  const int nwg = gridDim.x;
  const int q8 = nwg >> 3, r8 = nwg & 7;
  const int xcd = blockIdx.x & 7, pos = blockIdx.x >> 3;
  const int wg = (xcd < r8 ? xcd * (q8 + 1) : r8 * (q8 + 1) + (xcd - r8) * q8) + pos;
  const size_t bm = (size_t)(wg / NBN) * 256;
  const int bn = (wg % NBN) * 64;

  f32x4 acc[4][4];
  #pragma unroll
  for (int m = 0; m < 4; m++)
    #pragma unroll
    for (int n = 0; n < 4; n++)
      acc[m][n] = f32x4{0.f, 0.f, 0.f, 0.f};

  const int rsub = lane >> 2;                        // 0..15 rows within a 16-row stripe
  const int gsw  = (lane & 3) ^ ((lane >> 4) & 3);   // swizzled global granule for staging
  const int csub = gsw * 8;                          // k-element offset (16B granule)

  auto stage = [&](int buf, int k0){
    ushort* base = smem + buf * 20480;
    #pragma unroll
    for (int i = 0; i < 4; i++){
      int r = i * 64 + w * 16 + rsub;
      const ushort* gh = AH + (bm + r) * K + k0 + csub;
      const ushort* gl = AL + (bm + r) * K + k0 + csub;
      ushort* lph = base + (i * 64 + w * 16) * 32;        // wave-uniform base; HW adds lane*16B
      ushort* lpl = base + 8192 + (i * 64 + w * 16) * 32;
      __builtin_amdgcn_global_load_lds((const __attribute__((address_space(1))) void*)gh,
                                       (__attribute__((address_space(3))) void*)lph, 16, 0, 0);
      __builtin_amdgcn_global_load_lds((const __attribute__((address_space(1))) void*)gl,
                                       (__attribute__((address_space(3))) void*)lpl, 16, 0, 0);
    }
    {
      int r = w * 16 + rsub;
      const ushort* gh = BH + (size_t)(bn + r) * K + k0 + csub;
      const ushort* gl = BL + (size_t)(bn + r) * K + k0 + csub;
      ushort* lph = base + 16384 + (w * 16) * 32;
      ushort* lpl = base + 18432 + (w * 16) * 32;
      __builtin_amdgcn_global_load_lds((const __attribute__((address_space(1))) void*)gh,
                                       (__attribute__((address_space(3))) void*)lph, 16, 0, 0);
      __builtin_amdgcn_global_load_lds((const __attribute__((address_space(1))) void*)gl,
                                       (__attribute__((address_space(3))) void*)lpl, 16, 0, 0);
    }
  };

  const int NT = K / 32;
  stage(0, 0);
  __syncthreads();                 // drains prologue staging
  int cur = 0;
  for (int t = 0; t < NT; t++){
    if (t + 1 < NT) stage(cur ^ 1, (t + 1) * 32);   // prefetch next tile first
    ushort* base = smem + cur * 20480;
    short8v ah[4], al[4], bh[4], bl[4];
    const int kg = lane >> 4;
    const int mrow = lane & 15;
    const int krow = (kg ^ (mrow >> 2)) * 8;        // swizzled slot
    #pragma unroll
    for (int m = 0; m < 4; m++){
      ah[m] = *(const short8v*)(base + (w * 64 + m * 16 + mrow) * 32 + krow);
      al[m] = *(const short8v*)(base + 8192 + (w * 64 + m * 16 + mrow) * 32 + krow);
    }
    #pragma unroll
    for (int n = 0; n < 4; n++){
      bh[n] = *(const short8v*)(base + 16384 + (n * 16 + mrow) * 32 + krow);
      bl[n] = *(const short8v*)(base + 18432 + (n * 16 + mrow) * 32 + krow);
    }
    #pragma unroll
    for (int m = 0; m < 4; m++)
      #pragma unroll
      for (int n = 0; n < 4; n++){
        acc[m][n] = __builtin_amdgcn_mfma_f32_16x16x32_bf16(al[m], bh[n], acc[m][n], 0, 0, 0);
        acc[m][n] = __builtin_amdgcn_mfma_f32_16x16x32_bf16(ah[m], bl[n], acc[m][n], 0, 0, 0);
        acc[m][n] = __builtin_amdgcn_mfma_f32_16x16x32_bf16(ah[m], bh[n], acc[m][n], 0, 0, 0);
      }
    __syncthreads();               // reads of buf[cur] done + buf[cur^1] staged
    cur ^= 1;
  }

  float s1[4], s2[4];
  #pragma unroll
  for (int n = 0; n < 4; n++){ s1[n] = 0.f; s2[n] = 0.f; }

  const size_t rbase = bm + w * 64 + ((lane >> 4) * 4);
  #pragma unroll
  for (int n = 0; n < 4; n++){
    int c = bn + n * 16 + (lane & 15);
    float bv = bias[c];
    #pragma unroll
    for (int m = 0; m < 4; m++){
      #pragma unroll
      for (int j = 0; j < 4; j++){
        size_t r = rbase + m * 16 + j;
        float v = acc[m][n][j] + bv;
        if (RELU) v = fmaxf(v, 0.f);
        ushort hi = f2bf(v);
        outh[r * LDC + c] = hi;
        outl[r * LDC + c] = f2bf(v - bf2f(hi));
        if (STATS){
          if (r < (size_t)Nrows){ s1[n] += v; s2[n] += v * v; }
        }
      }
    }
  }

  if (STATS){
    float* sred = (float*)smem;    // aliased into staging LDS (k-loop done, barrier passed)
    if (tid < 128) sred[tid] = 0.f;
    __syncthreads();
    #pragma unroll
    for (int n = 0; n < 4; n++){
      float a = s1[n], b = s2[n];
      a += __shfl_xor(a, 16, 64); b += __shfl_xor(b, 16, 64);
      a += __shfl_xor(a, 32, 64); b += __shfl_xor(b, 32, 64);
      if (lane < 16){
        atomicAdd(&sred[n * 16 + lane], a);
        atomicAdd(&sred[64 + n * 16 + lane], b);
      }
    }
    __syncthreads();
    if (tid < 64){
      atomicAdd(&bnacc[bn + tid], sred[tid]);
      atomicAdd(&bnacc[D1 + bn + tid], sred[64 + tid]);
    }
  }
}

// ---------------- batch norm finalize ----------------
__global__ void k_bnfin(const float* __restrict__ accu, const float* __restrict__ gp,
                        const float* __restrict__ bp, int l, float* __restrict__ scsh, int N){
  int c = threadIdx.x;
  if (c >= D1) return;
  float invN = 1.0f / (float)N;
  float mu = accu[c] * invN;
  float var = accu[D1 + c] * invN - mu * mu;
  var = fmaxf(var, 0.f);
  float sc = gp[l * D1 + c] * rsqrtf(var + 1e-5f);
  scsh[c] = sc;
  scsh[D1 + c] = bp[l * D1 + c] - mu * sc;
}

// ---------------- readout: per-graph mean of BN(zh+zl) (graph_ids sorted; affine after mean) --
__device__ __forceinline__ int lbound(const int* a, int n, int v){
  int lo = 0, hi = n;
  while (lo < hi){
    int mid = (lo + hi) >> 1;
    if (a[mid] < v) lo = mid + 1; else hi = mid;
  }
  return lo;
}
__global__ __launch_bounds__(128) void k_readout(const ushort* __restrict__ zh,
                                                 const ushort* __restrict__ zl,
                                                 const float* __restrict__ scsh,
                                                 const int* __restrict__ gid,
                                                 float* __restrict__ out, int N){
  int g = blockIdx.x;
  int t = threadIdx.x;
  if (t >= 75) return;  // 75*4 = 300 cols
  int s = lbound(gid, N, g);
  int e = lbound(gid, N, g + 1);
  float a0 = 0.f, a1 = 0.f, a2 = 0.f, a3 = 0.f;
  for (int r = s; r < e; r++){
    uint2 uh = *(const uint2*)(zh + (size_t)r * D1 + t * 4);
    uint2 ul = *(const uint2*)(zl + (size_t)r * D1 + t * 4);
    const ushort* ph = (const ushort*)&uh;
    const ushort* pl = (const ushort*)&ul;
    a0 += bf2f(ph[0]) + bf2f(pl[0]);
    a1 += bf2f(ph[1]) + bf2f(pl[1]);
    a2 += bf2f(ph[2]) + bf2f(pl[2]);
    a3 += bf2f(ph[3]) + bf2f(pl[3]);
  }
  int c = t * 4;
  int cnt = e - s;
  if (cnt <= 0){
    out[(size_t)g * EMB + c + 0] = 0.f;
    out[(size_t)g * EMB + c + 1] = 0.f;
    out[(size_t)g * EMB + c + 2] = 0.f;
    out[(size_t)g * EMB + c + 3] = 0.f;
    return;
  }
  float inv = 1.0f / (float)cnt;
  float4 sc = *(const float4*)(scsh + c);
  float4 sh = *(const float4*)(scsh + D1 + c);
  out[(size_t)g * EMB + c + 0] = fmaf(a0 * inv, sc.x, sh.x);
  out[(size_t)g * EMB + c + 1] = fmaf(a1 * inv, sc.y, sh.y);
  out[(size_t)g * EMB + c + 2] = fmaf(a2 * inv, sc.z, sh.z);
  out[(size_t)g * EMB + c + 3] = fmaf(a3 * inv, sc.w, sh.w);
}

// ---------------- launch ----------------
extern "C" void kernel_launch(void* const* d_in, const int* in_sizes, int n_in,
                              void* d_out, int out_size, void* d_ws, size_t ws_size,
                              hipStream_t stream){
  const float* node_feats = (const float*)d_in[0];
  const float* W1    = (const float*)d_in[1];
  const float* b1    = (const float*)d_in[2];
  const float* W2    = (const float*)d_in[3];
  const float* b2    = (const float*)d_in[4];
  const float* eps   = (const float*)d_in[5];
  const float* gamma = (const float*)d_in[6];
  const float* beta  = (const float*)d_in[7];
  const int* src = (const int*)d_in[8];
  const int* dst = (const int*)d_in[9];
  const int* gid = (const int*)d_in[10];

  const int N = in_sizes[0] / EMB;
  const int E = in_sizes[8];
  const int G = out_size / EMB;
  const int MPAD = ((N + 255) / 256) * 256;

  char* ws = (char*)d_ws;
  // 3 segments of seg = MPAD*D1*4 B (= MPAD*D2*2 B). Roles rotate per layer:
  //   zin  = (l odd) ? S1 : S0   holds z(l-1) as [zh | zl] halves (read by aggregate)
  //   xseg = (l odd) ? S0 : S1   holds x as [xh | xl] (agg -> gemm1), then z(l) [zh | zl]
  //   yh -> whole zin seg (z dead after agg), yl -> whole S2   (y live gemm1 -> gemm2)
  const size_t seg  = (size_t)MPAD * D1 * 4;
  const size_t half = (size_t)MPAD * D1;     // ushort offset of the lo plane
  char* S0 = ws;
  char* S1 = ws + seg;
  char* S2 = ws + 2 * seg;

  size_t off = 3 * seg;
  auto alloc = [&](size_t b){ size_t o = off; off += (b + 255) & ~(size_t)255; return o; };
  ushort* w1h  = (ushort*)(ws + alloc((size_t)NLAYER * D2 * D1 * 2));
  ushort* w1l  = (ushort*)(ws + alloc((size_t)NLAYER * D2 * D1 * 2));
  ushort* w2h  = (ushort*)(ws + alloc((size_t)NLAYER * D1 * D2 * 2));
  ushort* w2l  = (ushort*)(ws + alloc((size_t)NLAYER * D1 * D2 * 2));
  float* b1p = (float*)(ws + alloc(NLAYER * D2 * 4));
  float* b2p = (float*)(ws + alloc(NLAYER * D1 * 4));
  float* gp  = (float*)(ws + alloc(NLAYER * D1 * 4));
  float* bp  = (float*)(ws + alloc(NLAYER * D1 * 4));
  int* deg     = (int*)(ws + alloc((size_t)N * 4));
  int* row_ptr = (int*)(ws + alloc((size_t)(N + 1) * 4));
  int* cursor  = (int*)(ws + alloc((size_t)N * 4));
  int* ssrc    = (int*)(ws + alloc((size_t)E * 4));
  float* bnacc = (float*)(ws + alloc(2 * D1 * 4));
  float* scsh  = (float*)(ws + alloc(2 * D1 * 4));
  float* scsh0 = (float*)(ws + alloc(2 * D1 * 4));

  k_prep_w1<<<(NLAYER * D2 * D1 + 255) / 256, 256, 0, stream>>>(W1, w1h, w1l);
  k_prep_w2<<<(NLAYER * D1 * D2 + 255) / 256, 256, 0, stream>>>(W2, w2h, w2l);
  k_prep_vec<<<(NLAYER * D2 + 255) / 256, 256, 0, stream>>>(b1, b2, gamma, beta,
                                                            b1p, b2p, gp, bp, scsh0);
  k_hinit<<<((size_t)N * 80 + 255) / 256, 256, 0, stream>>>(node_feats,
                                                            (ushort*)S0, (ushort*)S0 + half, N);

  hipMemsetAsync(deg, 0, (size_t)N * 4, stream);
  k_count<<<(E + 255) / 256, 256, 0, stream>>>(dst, deg, E);
  k_scan<<<1, 1024, 0, stream>>>(deg, row_ptr, cursor, N);
  k_scatter<<<(E + 255) / 256, 256, 0, stream>>>(src, dst, cursor, ssrc, E);

  for (int l = 0; l < NLAYER; l++){
    char* zin  = (l & 1) ? S1 : S0;
    char* xsg  = (l & 1) ? S0 : S1;
    ushort* zh = (ushort*)zin;
    ushort* zl = zh + half;
    ushort* xh = (ushort*)xsg;
    ushort* xl = xh + half;
    ushort* yh = (ushort*)zin;   // overwrites z (dead after aggregate)
    ushort* yl = (ushort*)S2;
    ushort* zoh = (ushort*)xsg;  // z(l) hi plane (overwrites x, dead after gemm1)
    ushort* zol = zoh + half;
    const float* scin = (l == 0) ? scsh0 : scsh;

    k_aggregate<<<(N + 7) / 8, 320, 0, stream>>>(zh, zl, scin, xh, xl,
                                                 row_ptr, ssrc, eps, l, (l > 0) ? 1 : 0, N);
    k_gemm<D1, D2, D2/64, true, false><<<(MPAD / 256) * (D2 / 64), 256, 0, stream>>>(
        xh, xl, w1h + (size_t)l * D2 * D1, w1l + (size_t)l * D2 * D1,
        b1p + l * D2, yh, yl, nullptr, 0);
    hipMemsetAsync(bnacc, 0, 2 * D1 * 4, stream);
    k_gemm<D2, D1, D1/64, false, true><<<(MPAD / 256) * (D1 / 64), 256, 0, stream>>>(
        yh, yl, w2h + (size_t)l * D1 * D2, w2l + (size_t)l * D1 * D2,
        b2p + l * D1, zoh, zol, bnacc, N);
    k_bnfin<<<1, D1, 0, stream>>>(bnacc, gp, bp, l, scsh, N);
  }
  // final z is in xseg of layer 4 = S1
  k_readout<<<G, 128, 0, stream>>>((ushort*)S1, (ushort*)S1 + half, scsh, gid,
                                   (float*)d_out, N);
}